// Round 2
// baseline (89.153 us; speedup 1.0000x reference)
//
#include <hip/hip_runtime.h>
#include <math.h>

// Problem constants (from reference):
// x: (32, 256, 112, 112) fp32, W: (1, 2, 7, 7) fp32, out: (32, 1, 112, 112) fp32
#define BATCH 32
#define CH    256
#define HH    112
#define WW    112
#define HW    (HH * WW)     // 12544
#define HW4   (HW / 4)      // 3136

#define CG    4             // channel groups per block
#define CPG   (CH / CG)     // 64 channels per group
#define SPB   64            // spatial float4s per block (one wave-width)

// ---------------------------------------------------------------------------
// Kernel 1: channel-wise mean + max reduction, channel-split for occupancy.
// Block = 256 threads = 64 spatial-float4 positions x 4 channel groups.
// Each wave (fixed cg) reads 64 consecutive float4s per c -> coalesced 1 KiB
// loads. 64 c-iterations per thread. LDS combine of the 4 partials.
// Grid = 32 x 49 = 1568 blocks (~6 blocks/CU vs 1.5 before).
// ---------------------------------------------------------------------------
__global__ __launch_bounds__(256) void sa_pool_kernel(
    const float4* __restrict__ x4,
    float4* __restrict__ avg4,
    float4* __restrict__ max4)
{
    __shared__ float4 ps[CG][SPB];
    __shared__ float4 pm[CG][SPB];

    int tid = threadIdx.x;
    int sp  = tid & 63;        // spatial float4 within block
    int cg  = tid >> 6;        // channel group (= wave id)
    int b   = blockIdx.y;
    int q   = blockIdx.x * SPB + sp;   // float4 index within the HxW plane

    const float4* p = x4 + (size_t)b * (CH * HW4) + (size_t)(cg * CPG) * HW4 + q;

    float4 s = make_float4(0.f, 0.f, 0.f, 0.f);
    float4 m = make_float4(-INFINITY, -INFINITY, -INFINITY, -INFINITY);

    #pragma unroll 8
    for (int c = 0; c < CPG; ++c) {
        float4 v = p[(size_t)c * HW4];
        s.x += v.x; s.y += v.y; s.z += v.z; s.w += v.w;
        m.x = fmaxf(m.x, v.x);
        m.y = fmaxf(m.y, v.y);
        m.z = fmaxf(m.z, v.z);
        m.w = fmaxf(m.w, v.w);
    }

    ps[cg][sp] = s;
    pm[cg][sp] = m;
    __syncthreads();

    if (cg == 0) {
        float4 s0 = ps[0][sp], s1 = ps[1][sp], s2 = ps[2][sp], s3 = ps[3][sp];
        float4 m0 = pm[0][sp], m1 = pm[1][sp], m2 = pm[2][sp], m3 = pm[3][sp];

        const float inv = 1.0f / (float)CH;
        float4 a;
        a.x = (s0.x + s1.x + s2.x + s3.x) * inv;
        a.y = (s0.y + s1.y + s2.y + s3.y) * inv;
        a.z = (s0.z + s1.z + s2.z + s3.z) * inv;
        a.w = (s0.w + s1.w + s2.w + s3.w) * inv;

        float4 mm;
        mm.x = fmaxf(fmaxf(m0.x, m1.x), fmaxf(m2.x, m3.x));
        mm.y = fmaxf(fmaxf(m0.y, m1.y), fmaxf(m2.y, m3.y));
        mm.z = fmaxf(fmaxf(m0.z, m1.z), fmaxf(m2.z, m3.z));
        mm.w = fmaxf(fmaxf(m0.w, m1.w), fmaxf(m2.w, m3.w));

        int g = b * HW4 + q;
        avg4[g] = a;
        max4[g] = mm;
    }
}

// ---------------------------------------------------------------------------
// Kernel 2: 7x7 conv (2 in-ch -> 1 out-ch, pad 3) + sigmoid.
// 16x16 output tile / block; halo tile 22x22 per channel in LDS; weights in
// LDS. 112/16 = 7 exactly -> no output bounds checks.
// ---------------------------------------------------------------------------
#define TILE 16
#define TW   (TILE + 6)     // 22

__global__ __launch_bounds__(256) void sa_conv_kernel(
    const float* __restrict__ avgp,
    const float* __restrict__ maxp,
    const float* __restrict__ wt,    // [2][7][7] flat (O=1, OIHW)
    float* __restrict__ out)
{
    __shared__ float t0[TW][TW];
    __shared__ float t1[TW][TW];
    __shared__ float w[2][49];

    int tid = threadIdx.x;
    int b   = blockIdx.z;
    int ty0 = blockIdx.y * TILE;
    int tx0 = blockIdx.x * TILE;

    if (tid < 98) w[tid / 49][tid % 49] = wt[tid];

    const float* ap = avgp + b * HW;
    const float* mp = maxp + b * HW;

    for (int idx = tid; idx < TW * TW; idx += 256) {
        int iy = idx / TW;
        int ix = idx - iy * TW;
        int gy = ty0 + iy - 3;
        int gx = tx0 + ix - 3;
        bool ok = (gy >= 0) && (gy < HH) && (gx >= 0) && (gx < WW);
        int gofs = gy * WW + gx;
        t0[iy][ix] = ok ? ap[gofs] : 0.0f;
        t1[iy][ix] = ok ? mp[gofs] : 0.0f;
    }
    __syncthreads();

    int oy = tid >> 4;          // 0..15
    int ox = tid & 15;          // 0..15

    float acc = 0.0f;
    #pragma unroll
    for (int i = 0; i < 7; ++i) {
        #pragma unroll
        for (int j = 0; j < 7; ++j) {
            acc += w[0][i * 7 + j] * t0[oy + i][ox + j];
            acc += w[1][i * 7 + j] * t1[oy + i][ox + j];
        }
    }

    float y = 1.0f / (1.0f + expf(-acc));
    out[b * HW + (ty0 + oy) * WW + (tx0 + ox)] = y;
}

// ---------------------------------------------------------------------------
extern "C" void kernel_launch(void* const* d_in, const int* in_sizes, int n_in,
                              void* d_out, int out_size, void* d_ws, size_t ws_size,
                              hipStream_t stream)
{
    const float* x  = (const float*)d_in[0];
    const float* wt = (const float*)d_in[1];
    float* out = (float*)d_out;

    // workspace: avg plane then max plane, each BATCH*HW floats (1.6 MB each)
    float* avgp = (float*)d_ws;
    float* maxp = avgp + (size_t)BATCH * HW;

    // Kernel 1: 49 x 32 = 1568 blocks of 256
    dim3 grid1(HW4 / SPB, BATCH);
    sa_pool_kernel<<<grid1, 256, 0, stream>>>(
        (const float4*)x, (float4*)avgp, (float4*)maxp);

    // Kernel 2: 7x7 tiles, 32 batches
    dim3 grid2(WW / TILE, HH / TILE, BATCH);
    sa_conv_kernel<<<grid2, 256, 0, stream>>>(avgp, maxp, wt, out);
}

// Round 3
// 83.760 us; speedup vs baseline: 1.0644x; 1.0644x over previous
//
#include <hip/hip_runtime.h>
#include <math.h>

// Problem constants (from reference):
// x: (32, 256, 112, 112) fp32, W: (1, 2, 7, 7) fp32, out: (32, 1, 112, 112) fp32
#define BATCH 32
#define CH    256
#define HH    112
#define WW    112
#define HW    (HH * WW)     // 12544
#define HW4   (HW / 4)      // 3136 = 7 * 448

#define CHUNK 448           // float4s per block (7 waves x 64 lanes)

// ---------------------------------------------------------------------------
// Kernel 1: channel-wise mean + max reduction.
// Block = 448 threads (7 waves), each thread owns one float4 spatial position.
// Per channel step the block reads 448 x 16B = 7 KiB CONTIGUOUS (vs 1-4 KiB
// in earlier rounds) -> better DRAM row-activate amortization for the
// 50 KiB-strided channel walk. No LDS, no combine. Grid = 7 x 32 = 224.
// ---------------------------------------------------------------------------
__global__ __launch_bounds__(448) void sa_pool_kernel(
    const float4* __restrict__ x4,
    float4* __restrict__ avg4,
    float4* __restrict__ max4)
{
    int tid = threadIdx.x;
    int b   = blockIdx.y;
    int q   = blockIdx.x * CHUNK + tid;   // float4 index within the HxW plane

    const float4* p = x4 + (size_t)b * (CH * HW4) + q;

    float4 s = make_float4(0.f, 0.f, 0.f, 0.f);
    float4 m = make_float4(-INFINITY, -INFINITY, -INFINITY, -INFINITY);

    #pragma unroll 8
    for (int c = 0; c < CH; ++c) {
        float4 v = p[(size_t)c * HW4];
        s.x += v.x; s.y += v.y; s.z += v.z; s.w += v.w;
        m.x = fmaxf(m.x, v.x);
        m.y = fmaxf(m.y, v.y);
        m.z = fmaxf(m.z, v.z);
        m.w = fmaxf(m.w, v.w);
    }

    const float inv = 1.0f / (float)CH;
    float4 a = make_float4(s.x * inv, s.y * inv, s.z * inv, s.w * inv);

    int g = b * HW4 + q;
    avg4[g] = a;
    max4[g] = m;
}

// ---------------------------------------------------------------------------
// Kernel 2: 7x7 conv (2 in-ch -> 1 out-ch, pad 3) + sigmoid.
// 16x16 output tile / block; halo tile 22x22 per channel in LDS; weights in
// LDS. 112/16 = 7 exactly -> no output bounds checks.
// ---------------------------------------------------------------------------
#define TILE 16
#define TW   (TILE + 6)     // 22

__global__ __launch_bounds__(256) void sa_conv_kernel(
    const float* __restrict__ avgp,
    const float* __restrict__ maxp,
    const float* __restrict__ wt,    // [2][7][7] flat (O=1, OIHW)
    float* __restrict__ out)
{
    __shared__ float t0[TW][TW];
    __shared__ float t1[TW][TW];
    __shared__ float w[2][49];

    int tid = threadIdx.x;
    int b   = blockIdx.z;
    int ty0 = blockIdx.y * TILE;
    int tx0 = blockIdx.x * TILE;

    if (tid < 98) w[tid / 49][tid % 49] = wt[tid];

    const float* ap = avgp + b * HW;
    const float* mp = maxp + b * HW;

    for (int idx = tid; idx < TW * TW; idx += 256) {
        int iy = idx / TW;
        int ix = idx - iy * TW;
        int gy = ty0 + iy - 3;
        int gx = tx0 + ix - 3;
        bool ok = (gy >= 0) && (gy < HH) && (gx >= 0) && (gx < WW);
        int gofs = gy * WW + gx;
        t0[iy][ix] = ok ? ap[gofs] : 0.0f;
        t1[iy][ix] = ok ? mp[gofs] : 0.0f;
    }
    __syncthreads();

    int oy = tid >> 4;          // 0..15
    int ox = tid & 15;          // 0..15

    float acc = 0.0f;
    #pragma unroll
    for (int i = 0; i < 7; ++i) {
        #pragma unroll
        for (int j = 0; j < 7; ++j) {
            acc += w[0][i * 7 + j] * t0[oy + i][ox + j];
            acc += w[1][i * 7 + j] * t1[oy + i][ox + j];
        }
    }

    float y = 1.0f / (1.0f + expf(-acc));
    out[b * HW + (ty0 + oy) * WW + (tx0 + ox)] = y;
}

// ---------------------------------------------------------------------------
extern "C" void kernel_launch(void* const* d_in, const int* in_sizes, int n_in,
                              void* d_out, int out_size, void* d_ws, size_t ws_size,
                              hipStream_t stream)
{
    const float* x  = (const float*)d_in[0];
    const float* wt = (const float*)d_in[1];
    float* out = (float*)d_out;

    // workspace: avg plane then max plane, each BATCH*HW floats (1.6 MB each)
    float* avgp = (float*)d_ws;
    float* maxp = avgp + (size_t)BATCH * HW;

    // Kernel 1: 7 x 32 = 224 blocks of 448 threads (7 KiB contiguous / c-step)
    dim3 grid1(HW4 / CHUNK, BATCH);
    sa_pool_kernel<<<grid1, CHUNK, 0, stream>>>(
        (const float4*)x, (float4*)avgp, (float4*)maxp);

    // Kernel 2: 7x7 tiles, 32 batches
    dim3 grid2(WW / TILE, HH / TILE, BATCH);
    sa_conv_kernel<<<grid2, 256, 0, stream>>>(avgp, maxp, wt, out);
}